// Round 10
// baseline (392.917 us; speedup 1.0000x reference)
//
#include <hip/hip_runtime.h>

#define SDIM 2048
#define EDIM 2048
#define NHEAD 16
#define DHEAD 128

typedef __attribute__((ext_vector_type(8))) short short8;
typedef __attribute__((ext_vector_type(4))) float floatx4;

__device__ __forceinline__ float bf2f(ushort u) {
    union { uint i; float f; } v; v.i = ((uint)u) << 16; return v.f;
}
__device__ __forceinline__ ushort f2bf(float f) {
    union { float f; uint i; } v; v.f = f;
    uint r = v.i + 0x7fff + ((v.i >> 16) & 1);
    return (ushort)(r >> 16);
}

// async global->LDS, 16B per lane. LDS dest = wave-uniform base + lane*16.
__device__ __forceinline__ void gload_lds16(const ushort* g, ushort* l) {
    __builtin_amdgcn_global_load_lds(
        (const __attribute__((address_space(1))) void*)g,
        (__attribute__((address_space(3))) void*)l, 16, 0, 0);
}

// ---------------- fused fp32 -> bf16 conversion (4 matrices; Wo is ----------
// converted inside the QKV launch on its idle CUs) ---------------------------
// NOTE (R7/R8 lesson): do NOT fuse the KV-split merge into attn via
// device-scope __threadfence — on 8-XCD gfx950 each fence is an L2
// writeback; 1024-1536 of them serialized per-XCD cost ~200us (attn went
// 70 -> 212/255us). A separate merge kernel + launch gap is ~10x cheaper.
__global__ void convert4_kernel(
    const float* __restrict__ s0, const float* __restrict__ s1,
    const float* __restrict__ s2, const float* __restrict__ s3,
    ushort* __restrict__ d0, ushort* __restrict__ d1,
    ushort* __restrict__ d2, ushort* __restrict__ d3)
{
    const float* src; ushort* dst;
    switch (blockIdx.y) {
        case 0: src = s0; dst = d0; break;
        case 1: src = s1; dst = d1; break;
        case 2: src = s2; dst = d2; break;
        default: src = s3; dst = d3; break;
    }
    int i = blockIdx.x * blockDim.x + threadIdx.x;
    float4 f = ((const float4*)src)[i];
    ushort4 o;
    o.x = f2bf(f.x); o.y = f2bf(f.y); o.z = f2bf(f.z); o.w = f2bf(f.w);
    ((ushort4*)dst)[i] = o;
}

#define QPRESCALE 0.12754245f   // (1/sqrt(128)) * log2(e)

// ======================================================================
// 256x256-tile deep-pipelined bf16 GEMM (C = A*B^T + bias), fused QKV.
// 8 waves (2M x 4N), BK=64, double-buffered 128 KiB LDS, counted vmcnt.
// 4 phases per K-tile, reads balanced 8/8/4/4 via kk-split. (R4's 3-phase
// merge REGRESSED in-profile — structure frozen at the R3 form.)
//   ph0: A-h0 kk0 + B kk0 (all 4 an) -> MFMA h0 x kk0
//   ph1: A-h0 kk1 + B kk1           -> MFMA h0 x kk1
//   ph2: A-h1 kk0 (B kk0 in regs)   -> MFMA h1 x kk0
//   ph3: A-h1 kk1 (B kk1 in regs)   -> MFMA h1 x kk1; vmcnt(4); barrier
// Staging: tile t stages A(t+1) in ph0/ph1, B(t+2) in ph2/ph3. vmcnt(4)
// at tile end keeps B(t+2) in flight; A(t+1)+B(t+1) proven landed.
// LDS XOR swizzle chunk^=(row&7) via pre-swizzled GLOBAL source
// (gload_lds writes linearly) + swizzled ds_read addr (both-sides rule).
// which: 0=Q (RoPE+QPRESCALE), 1=K (RoPE), 2=V (transposed Vt[h][d][s]).
// grid (8, 32): y in [24,32) = 64 filler blocks convert Wo fp32->bf16
// (192 GEMM + 64 convert = 256 blocks = 1/CU; Wo hidden under GEMM).
// ======================================================================
__global__ __launch_bounds__(512, 2) void gemm256_qkv(
    const ushort* __restrict__ A,
    const ushort* __restrict__ B0, const ushort* __restrict__ B1, const ushort* __restrict__ B2,
    const float* __restrict__ s0, const float* __restrict__ s1, const float* __restrict__ s2,
    ushort* __restrict__ C0, ushort* __restrict__ C1, ushort* __restrict__ Vtg,
    const float* __restrict__ WoF, ushort* __restrict__ WoB)
{
    // [buf][A=0/B=1][half][128 rows][64 k] bf16 = 128 KiB
    __shared__ __align__(16) ushort smem[2][2][2][128 * 64];

    const int tid  = threadIdx.x;

    if (blockIdx.y >= 24) {
        // ---- Wo conversion on the 64 filler blocks (no LDS, no barriers) ----
        const int idx = (blockIdx.y - 24) * 8 + blockIdx.x;   // [0,64)
        const float4* src = (const float4*)WoF;
#pragma unroll
        for (int it = 0; it < 32; ++it) {
            int i = idx * 16384 + it * 512 + tid;             // 64*16384*4 = 2048^2
            float4 f = src[i];
            ushort4 o;
            o.x = f2bf(f.x); o.y = f2bf(f.y); o.z = f2bf(f.z); o.w = f2bf(f.w);
            ((ushort4*)WoB)[i] = o;
        }
        return;
    }

    const int lane = tid & 63;
    const int wave = tid >> 6;
    const int l15 = lane & 15, quad = lane >> 4, l7 = lane & 7;
    const int wm = wave & 1, wn = wave >> 1;
    const int bm = blockIdx.x * 256;
    const int which = blockIdx.y >> 3;
    const int n0 = (blockIdx.y & 7) * 256;
    const int NT = EDIM / 64;   // 32

    const ushort* Bsel = (which == 0) ? B0 : (which == 1) ? B1 : B2;
    const float*  bia  = (which == 0) ? s0 : (which == 1) ? s1 : s2;

    // staging coords: thread covers rows (tid>>3) and (tid>>3)+64 of a
    // 128-row half, 16B chunk (tid&7); global chunk pre-swizzled by row&7.
    const int srow = tid >> 3;
    const int sgc  = (((tid & 7) ^ ((tid >> 3) & 7)) << 3); // ushorts

    floatx4 acc[8][4];
#pragma unroll
    for (int i = 0; i < 8; i++)
#pragma unroll
        for (int j = 0; j < 4; j++) acc[i][j] = (floatx4)0.0f;

    auto stageA = [&](int tile, int h) {
        const ushort* g = A + (size_t)(bm + h * 128 + srow) * EDIM + tile * 64 + sgc;
        ushort* l = &smem[tile & 1][0][h][0] + tid * 8;
        gload_lds16(g, l);
        gload_lds16(g + (size_t)64 * EDIM, l + 4096);
    };
    auto stageB = [&](int tile, int h) {
        const ushort* g = Bsel + (size_t)(n0 + h * 128 + srow) * EDIM + tile * 64 + sgc;
        ushort* l = &smem[tile & 1][1][h][0] + tid * 8;
        gload_lds16(g, l);
        gload_lds16(g + (size_t)64 * EDIM, l + 4096);
    };

    // prologue: tile 0 complete + B(1); drain through tile 0 (B(1) stays in flight)
    stageA(0, 0); stageA(0, 1); stageB(0, 0); stageB(0, 1);
    stageB(1, 0); stageB(1, 1);
    asm volatile("s_waitcnt vmcnt(4)" ::: "memory");
    __builtin_amdgcn_s_barrier();

    const int c0 = ((quad ^ l7) << 3);         // kk=0 swizzled chunk (ushorts)
    const int c1 = (((quad + 4) ^ l7) << 3);   // kk=1
    const int brow0 = (wn & 1) * 64;           // wave's B rows within its half

    short8 af[4], b0[4], b1[4];

#define MFMA16(AOFF, AF, BF) \
    _Pragma("unroll") \
    for (int mf = 0; mf < 4; mf++) \
        _Pragma("unroll") \
        for (int an = 0; an < 4; an++) \
            acc[(AOFF) + mf][an] = __builtin_amdgcn_mfma_f32_16x16x32_bf16( \
                AF[mf], BF[an], acc[(AOFF) + mf][an], 0, 0, 0);

#define PH_PRE() do { \
    asm volatile("" ::: "memory"); \
    __builtin_amdgcn_s_barrier(); \
    asm volatile("s_waitcnt lgkmcnt(0)" ::: "memory"); \
    __builtin_amdgcn_sched_barrier(0); \
    __builtin_amdgcn_s_setprio(1); \
} while (0)
#define PH_POST() do { \
    __builtin_amdgcn_s_setprio(0); \
    asm volatile("" ::: "memory"); \
    __builtin_amdgcn_s_barrier(); \
} while (0)

    for (int t = 0; t < NT; ++t) {
        const ushort* aH = &smem[t & 1][0][wm][0];
        const ushort* bH = &smem[t & 1][1][wn >> 1][0];

        // ---- phase 0: read A-h0 kk0 (4) + B kk0 (4); stage A(t+1,h0); MFMA h0 x kk0
#pragma unroll
        for (int mf = 0; mf < 4; mf++)
            af[mf] = *(const short8*)(aH + (mf * 16 + l15) * 64 + c0);
#pragma unroll
        for (int an = 0; an < 4; an++)
            b0[an] = *(const short8*)(bH + (brow0 + an * 16 + l15) * 64 + c0);
        if (t + 1 < NT) stageA(t + 1, 0);
        PH_PRE();
        MFMA16(0, af, b0);
        PH_POST();

        // ---- phase 1: read A-h0 kk1 (4) + B kk1 (4); stage A(t+1,h1); MFMA h0 x kk1
        short8 ag[4];
#pragma unroll
        for (int mf = 0; mf < 4; mf++)
            ag[mf] = *(const short8*)(aH + (mf * 16 + l15) * 64 + c1);
#pragma unroll
        for (int an = 0; an < 4; an++)
            b1[an] = *(const short8*)(bH + (brow0 + an * 16 + l15) * 64 + c1);
        if (t + 1 < NT) stageA(t + 1, 1);
        PH_PRE();
        MFMA16(0, ag, b1);
        PH_POST();

        // ---- phase 2: read A-h1 kk0 (4); stage B(t+2,h0); MFMA h1 x kk0
#pragma unroll
        for (int mf = 0; mf < 4; mf++)
            af[mf] = *(const short8*)(aH + (64 + mf * 16 + l15) * 64 + c0);
        if (t + 2 < NT) stageB(t + 2, 0);
        PH_PRE();
        MFMA16(4, af, b0);
        PH_POST();

        // ---- phase 3: read A-h1 kk1 (4); stage B(t+2,h1); MFMA h1 x kk1; vmcnt
#pragma unroll
        for (int mf = 0; mf < 4; mf++)
            ag[mf] = *(const short8*)(aH + (64 + mf * 16 + l15) * 64 + c1);
        if (t + 2 < NT) stageB(t + 2, 1);
        asm volatile("" ::: "memory");
        __builtin_amdgcn_s_barrier();
        asm volatile("s_waitcnt lgkmcnt(0)" ::: "memory");
        __builtin_amdgcn_sched_barrier(0);
        __builtin_amdgcn_s_setprio(1);
        MFMA16(4, ag, b1);
        __builtin_amdgcn_s_setprio(0);
        if (t < NT - 2) asm volatile("s_waitcnt vmcnt(4)" ::: "memory");
        else            asm volatile("s_waitcnt vmcnt(0)" ::: "memory");
        __builtin_amdgcn_s_barrier();
    }
#undef MFMA16
#undef PH_PRE
#undef PH_POST

    // ---------------- epilogues (all gloads drained by tail vmcnt(0)) ----------
    if (which == 2) {
        // V: transposed write Vt[h][d][s], 4 consecutive s packed per store
#pragma unroll
        for (int an = 0; an < 4; an++) {
            int col = n0 + wn * 64 + an * 16 + l15;
            int h = col >> 7, d = col & 127;
            float bv = bia[col];
            ushort* cp = Vtg + (size_t)h * SDIM * DHEAD + (size_t)d * SDIM;
#pragma unroll
            for (int am = 0; am < 8; am++) {
                int s = bm + wm * 128 + am * 16 + quad * 4;
                ushort4 pk;
                pk.x = f2bf(acc[am][an][0] + bv);
                pk.y = f2bf(acc[am][an][1] + bv);
                pk.z = f2bf(acc[am][an][2] + bv);
                pk.w = f2bf(acc[am][an][3] + bv);
                *(ushort4*)(cp + s) = pk;
            }
        }
    } else {
        // Q/K: fused RoPE. Pair (d, d+64) lives in partner wave (wave^2,
        // same wm, wn bit0 flipped = +-64 cols). Exchange via dead staging
        // LDS, TWO am-slices per barrier pair (64 KB of the 128 KB buffer).
        ushort* C = (which == 0) ? C0 : C1;
        const float psc = (which == 0) ? QPRESCALE : 1.0f;
        float* xch = (float*)smem;
        float bv[4], invf[4];
#pragma unroll
        for (int an = 0; an < 4; an++) {
            bv[an]   = bia[n0 + wn * 64 + an * 16 + l15];
            invf[an] = __expf((float)(an * 16 + l15) * -0.14391157f);  // 10000^(-i/64)
        }
        const int mybase = wave * 1024 + quad * 16 + l15;
        const int pbase  = (wave ^ 2) * 1024 + quad * 16 + l15;
        const int rowb = bm + wm * 128 + quad * 4;
#pragma unroll
        for (int am2 = 0; am2 < 4; am2++) {
            __syncthreads();
#pragma unroll
            for (int sl = 0; sl < 2; sl++) {
                int am = am2 * 2 + sl;
#pragma unroll
                for (int an = 0; an < 4; an++)
#pragma unroll
                    for (int r = 0; r < 4; r++)
                        xch[sl * 8192 + mybase + an * 256 + r * 64] = acc[am][an][r] + bv[an];
            }
            __syncthreads();
#pragma unroll
            for (int sl = 0; sl < 2; sl++) {
                int am = am2 * 2 + sl;
#pragma unroll
                for (int an = 0; an < 4; an++) {
                    int col = n0 + wn * 64 + an * 16 + l15;
#pragma unroll
                    for (int r = 0; r < 4; r++) {
                        int row = rowb + am * 16 + r;
                        float v = acc[am][an][r] + bv[an];
                        float w = xch[sl * 8192 + pbase + an * 256 + r * 64];
                        float ang = (float)row * invf[an];
                        float rev = ang * 0.15915494309f;
                        rev -= floorf(rev);
                        float arad = rev * 6.28318530718f;
                        float sn = __sinf(arad), cs = __cosf(arad);
                        float o = ((wn & 1) == 0) ? (v * cs - w * sn) : (v * cs + w * sn);
                        C[(size_t)row * EDIM + col] = f2bf(o * psc);
                    }
                }
            }
        }
    }
}

// ---------------- bf16 GEMM: C = A * B^T + bias (m97 structure) ----------------
// Used for the output projection (KSPLIT=2, 512 blocks = 2/CU) and the
// no-split fallback.
template <typename OUTT, int KSPLIT>
__global__ __launch_bounds__(256) void gemm_bt(
    const ushort* __restrict__ A,
    const ushort* __restrict__ B0, const ushort* __restrict__ B1, const ushort* __restrict__ B2,
    const float* __restrict__ s0, const float* __restrict__ s1, const float* __restrict__ s2,
    OUTT* __restrict__ C0, OUTT* __restrict__ C1, OUTT* __restrict__ C2,
    int nbpm)
{
    __shared__ __align__(16) ushort smem[2 * 128 * 32];
    ushort* a_s = smem;
    ushort* b_s = smem + 128 * 32;

    const int tid = threadIdx.x;
    const int wave = tid >> 6, lane = tid & 63;
    const int l15 = lane & 15, quad = lane >> 4;
    const int wm = wave & 1, wn = wave >> 1;
    const int bm = blockIdx.x * 128;
    const int which = blockIdx.y / nbpm;
    const int n0 = (blockIdx.y % nbpm) * 128;

    const ushort* B;
    const float*  bia;
    OUTT*         C;
    const ushort* Abase;
    if constexpr (KSPLIT == 2) {
        B = B0; bia = s0; C = C0;
        Abase = A + which * (EDIM / 2);
    } else {
        B   = (which == 0) ? B0 : (which == 1) ? B1 : B2;
        bia = (which == 0) ? s0 : (which == 1) ? s1 : s2;
        C   = (which == 0) ? C0 : (which == 1) ? C1 : C2;
        Abase = A;
    }
    const ushort* Bbase = (KSPLIT == 2) ? B + which * (EDIM / 2) : B;

    floatx4 acc[4][4];
#pragma unroll
    for (int i = 0; i < 4; i++)
#pragma unroll
        for (int j = 0; j < 4; j++) acc[i][j] = (floatx4)0.0f;

    const int t1 = tid + 256;
    const int row0 = tid >> 2, kc0 = (tid & 3) * 8;
    const int row1 = t1 >> 2,  kc1 = (t1 & 3) * 8;

    for (int k0 = 0; k0 < EDIM / KSPLIT; k0 += 32) {
        __syncthreads();
        gload_lds16(Abase + (size_t)(bm + row0) * EDIM + k0 + kc0, a_s + tid * 8);
        gload_lds16(Abase + (size_t)(bm + row1) * EDIM + k0 + kc1, a_s + t1 * 8);
        gload_lds16(Bbase + (size_t)(n0 + row0) * EDIM + k0 + kc0, b_s + tid * 8);
        gload_lds16(Bbase + (size_t)(n0 + row1) * EDIM + k0 + kc1, b_s + t1 * 8);
        __syncthreads();

        short8 af[4], bf[4];
#pragma unroll
        for (int mt = 0; mt < 4; mt++)
            af[mt] = *(const short8*)(a_s + (wm * 64 + mt * 16 + l15) * 32 + quad * 8);
#pragma unroll
        for (int nt = 0; nt < 4; nt++)
            bf[nt] = *(const short8*)(b_s + (wn * 64 + nt * 16 + l15) * 32 + quad * 8);
#pragma unroll
        for (int mt = 0; mt < 4; mt++)
#pragma unroll
            for (int nt = 0; nt < 4; nt++)
                acc[mt][nt] = __builtin_amdgcn_mfma_f32_16x16x32_bf16(af[mt], bf[nt], acc[mt][nt], 0, 0, 0);
    }

    if constexpr (KSPLIT == 2) {
#pragma unroll
        for (int nt = 0; nt < 4; nt++) {
            int col = n0 + wn * 64 + nt * 16 + l15;
            float bv = (which == 0) ? bia[col] : 0.0f;
#pragma unroll
            for (int mt = 0; mt < 4; mt++) {
#pragma unroll
                for (int r = 0; r < 4; r++) {
                    int row = bm + wm * 64 + mt * 16 + quad * 4 + r;
                    atomicAdd(&((float*)C)[(size_t)row * EDIM + col], acc[mt][nt][r] + bv);
                }
            }
        }
    } else {
#pragma unroll
        for (int nt = 0; nt < 4; nt++) {
            int col = n0 + wn * 64 + nt * 16 + l15;
            float bv = bia[col];
#pragma unroll
            for (int mt = 0; mt < 4; mt++) {
#pragma unroll
                for (int r = 0; r < 4; r++) {
                    int row = bm + wm * 64 + mt * 16 + quad * 4 + r;
                    float v = acc[mt][nt][r] + bv;
                    if constexpr (sizeof(OUTT) == 2)
                        ((ushort*)C)[(size_t)row * EDIM + col] = f2bf(v);
                    else
                        ((float*)C)[(size_t)row * EDIM + col] = v;
                }
            }
        }
    }
}

// ---------------- flash attention: S^T trick + fixed-max softmax ----------------
// s_setprio around MFMA clusters (T5). nsplit=2: grid 1024 = 4 blocks/CU
// (LDS exactly 40960 B — do not add any __shared__ bytes; +512 B drops to
// 3 blocks/CU and ~3x the runtime, R7). No in-kernel merge (R7/R8 lesson:
// device-scope fences = serialized per-XCD L2 writebacks, ~200us).
// R10: T14 async-STAGE split — tile t+1's K/V global loads are issued into
// registers during tile t's compute and written to LDS at the next staging
// phase (issue-early/write-late; same LDS layout, same 2 barriers/tile).
#define MFIX2 17.31234049f   // 12 * log2(e)
__global__ __launch_bounds__(256, 4) void attn_kernel(
    const ushort* __restrict__ Q, const ushort* __restrict__ K,
    const ushort* __restrict__ Vtg,
    ushort* __restrict__ Opart, float* __restrict__ Lsum,
    ushort* __restrict__ Ab, int nsplit)
{
    __shared__ __align__(16) ushort Ks[64 * 128];
    __shared__ __align__(16) ushort Vt[128 * 64];
    __shared__ __align__(16) ushort Ps[64 * 64];

    const int bid = blockIdx.x;
    const int head = bid & 15, qt = (bid >> 4) & 31, half = bid >> 9;
    const int tid = threadIdx.x, wave = tid >> 6, lane = tid & 63;
    const int l15 = lane & 15, quad = lane >> 4;
    const int l7 = l15 & 7;
    const int kstart = half * (SDIM / nsplit);
    const int ntile = (SDIM / nsplit) / 64;

    short8 qf[4];
    {
        int s = qt * 64 + wave * 16 + l15;
        const ushort* qp = Q + (size_t)s * EDIM + head * DHEAD;
#pragma unroll
        for (int kc = 0; kc < 4; kc++) qf[kc] = *(const short8*)(qp + kc * 32 + quad * 8);
    }

    floatx4 o[8];
#pragma unroll
    for (int i = 0; i < 8; i++) o[i] = (floatx4)0.0f;
    float lsum = 0.0f;

    const int krow = tid >> 4, kc8 = tid & 15;
    const int vd = tid >> 3, vc8 = tid & 7;
    const int prow = wave * 16 + l15;

    // T14 staging registers: next tile's K (4x16B) and V (4x16B)
    uint4 kr[4], vr[4];
    auto loadKV = [&](int kv) {
        const int k0 = kstart + kv * 64;
#pragma unroll
        for (int i = 0; i < 4; i++)
            kr[i] = *(const uint4*)(K + (size_t)(k0 + krow + i * 16) * EDIM + head * DHEAD + kc8 * 8);
#pragma unroll
        for (int i = 0; i < 4; i++)
            vr[i] = *(const uint4*)(Vtg + (size_t)head * SDIM * DHEAD + (size_t)(vd + i * 32) * SDIM + k0 + vc8 * 8);
    };
    loadKV(0);

    for (int kv = 0; kv < ntile; kv++) {
        __syncthreads();
        // write-late: regs -> LDS (compiler inserts vmcnt wait on reg use)
#pragma unroll
        for (int i = 0; i < 4; i++) {
            int row = krow + i * 16;
            *(uint4*)(Ks + row * 128 + ((kc8 ^ (row & 7)) << 3)) = kr[i];
        }
#pragma unroll
        for (int i = 0; i < 4; i++) {
            int d = vd + i * 32;
            *(uint4*)(Vt + d * 64 + ((vc8 ^ (d & 7)) << 3)) = vr[i];
        }
        __syncthreads();
        // issue-early: next tile's loads overlap this tile's compute
        if (kv + 1 < ntile) loadKV(kv + 1);

#pragma unroll
        for (int nt = 0; nt < 4; nt++) {
            floatx4 st = (floatx4)0.0f;
            __builtin_amdgcn_s_setprio(1);
#pragma unroll
            for (int kc = 0; kc < 4; kc++) {
                short8 kfr = *(const short8*)(Ks + (nt * 16 + l15) * 128 + (((kc * 4 + quad) ^ l7) << 3));
                st = __builtin_amdgcn_mfma_f32_16x16x32_bf16(kfr, qf[kc], st, 0, 0, 0);
            }
            __builtin_amdgcn_s_setprio(0);
            ushort4 pk;
            float p0 = __builtin_amdgcn_exp2f(st[0] - MFIX2);
            float p1 = __builtin_amdgcn_exp2f(st[1] - MFIX2);
            float p2 = __builtin_amdgcn_exp2f(st[2] - MFIX2);
            float p3 = __builtin_amdgcn_exp2f(st[3] - MFIX2);
            lsum += (p0 + p1) + (p2 + p3);
            pk.x = f2bf(p0); pk.y = f2bf(p1); pk.z = f2bf(p2); pk.w = f2bf(p3);
            int c2 = (nt * 2 + (quad >> 1)) ^ l7;
            *(ushort4*)(Ps + prow * 64 + (c2 << 3) + ((quad & 1) << 2)) = pk;
        }

        __builtin_amdgcn_s_setprio(1);
#pragma unroll
        for (int kc2 = 0; kc2 < 2; kc2++) {
            short8 af = *(const short8*)(Ps + prow * 64 + (((kc2 * 4 + quad) ^ l7) << 3));
#pragma unroll
            for (int nt2 = 0; nt2 < 8; nt2++) {
                short8 bfr = *(const short8*)(Vt + (nt2 * 16 + l15) * 64 + (((kc2 * 4 + quad) ^ l7) << 3));
                o[nt2] = __builtin_amdgcn_mfma_f32_16x16x32_bf16(af, bfr, o[nt2], 0, 0, 0);
            }
        }
        __builtin_amdgcn_s_setprio(0);
    }

    lsum += __shfl_xor(lsum, 16);
    lsum += __shfl_xor(lsum, 32);

    if (nsplit == 1) {
        float invl[4];
#pragma unroll
        for (int r = 0; r < 4; r++) invl[r] = 1.0f / __shfl(lsum, quad * 4 + r, 16);
#pragma unroll
        for (int nt2 = 0; nt2 < 8; nt2++) {
#pragma unroll
            for (int r = 0; r < 4; r++) {
                int s = qt * 64 + wave * 16 + quad * 4 + r;
                int d = nt2 * 16 + l15;
                Ab[(size_t)head * SDIM * DHEAD + (size_t)s * DHEAD + d] = f2bf(o[nt2][r] * invl[r]);
            }
        }
    } else {
        size_t pb = ((size_t)half * NHEAD + head) * SDIM * DHEAD;
#pragma unroll
        for (int nt2 = 0; nt2 < 8; nt2++) {
#pragma unroll
            for (int r = 0; r < 4; r++) {
                int s = qt * 64 + wave * 16 + quad * 4 + r;
                int d = nt2 * 16 + l15;
                Opart[pb + (size_t)s * DHEAD + d] = f2bf(o[nt2][r]);
            }
        }
        if (lane < 16)
            Lsum[((size_t)half * NHEAD + head) * SDIM + qt * 64 + wave * 16 + lane] = lsum;
    }
}

// ---------------- merge two KV-split partials (shared fixed max) ----------------
// R10: also zeroes `out` (2 float4/thread = 16MB over 2048 blocks) —
// replaces the hipMemsetAsync dispatch; stream order still puts all
// zeroing before the out-projection's atomics.
__global__ void merge_kernel(const ushort* __restrict__ Opart,
                             const float* __restrict__ Lsum,
                             ushort* __restrict__ Ab,
                             float* __restrict__ outz)
{
    const int HS = NHEAD * SDIM;
    int t = blockIdx.x * blockDim.x + threadIdx.x;

    // zero out: 2048*256 threads x 2 float4 = 4M floats = 16MB
    float4 z = {0.f, 0.f, 0.f, 0.f};
    ((float4*)outz)[t] = z;
    ((float4*)outz)[t + 524288] = z;

    int row = t >> 4, c8 = (t & 15) * 8;
    float inv = 1.0f / (Lsum[row] + Lsum[HS + row]);
    float acc[8] = {0, 0, 0, 0, 0, 0, 0, 0};
#pragma unroll
    for (int p = 0; p < 2; p++) {
        union { uint4 v; ushort u[8]; } a;
        a.v = *(const uint4*)(Opart + (size_t)p * HS * DHEAD + (size_t)row * DHEAD + c8);
#pragma unroll
        for (int j = 0; j < 8; j++) acc[j] += bf2f(a.u[j]);
    }
    union { uint4 v; ushort u[8]; } ro;
#pragma unroll
    for (int j = 0; j < 8; j++) ro.u[j] = f2bf(acc[j] * inv);
    *(uint4*)(Ab + (size_t)row * DHEAD + c8) = ro.v;
}

extern "C" void kernel_launch(void* const* d_in, const int* in_sizes, int n_in,
                              void* d_out, int out_size, void* d_ws, size_t ws_size,
                              hipStream_t stream) {
    (void)in_sizes; (void)n_in; (void)out_size;
    const float* x  = (const float*)d_in[0];
    const float* Wq = (const float*)d_in[1];
    const float* bq = (const float*)d_in[2];
    const float* Wk = (const float*)d_in[3];
    const float* bk = (const float*)d_in[4];
    const float* Wv = (const float*)d_in[5];
    const float* bv = (const float*)d_in[6];
    const float* Wo = (const float*)d_in[7];
    const float* bo = (const float*)d_in[8];
    float* out = (float*)d_out;

    char* ws = (char*)d_ws;
    const size_t SEG = (size_t)EDIM * EDIM * 2;  // 8 MB per bf16 matrix
    ushort* xb  = (ushort*)(ws + 0 * SEG);
    ushort* Wqb = (ushort*)(ws + 1 * SEG);
    ushort* Wkb = (ushort*)(ws + 2 * SEG);
    ushort* Wvb = (ushort*)(ws + 3 * SEG);
    ushort* Wob = (ushort*)(ws + 4 * SEG);
    ushort* Qb  = (ushort*)(ws + 5 * SEG);
    ushort* Kb  = (ushort*)(ws + 6 * SEG);
    ushort* Vtg = (ushort*)(ws + 7 * SEG);   // V pre-transposed [h][d][s]
    ushort* Ab  = (ushort*)(ws + 8 * SEG);
    ushort* Op  = (ushort*)(ws + 0 * SEG);   // attn partials reuse SEG0-1 (2 x 8MB)
    float*  Ls  = (float*)(ws + 11 * SEG);   // 2 x 32768 x 4B = 256KB

    const int split = (ws_size >= ((size_t)89 << 20)) ? 1 : 0;

    // x, Wq, Wk, Wv converted up front; Wo converted inside the QKV launch
    convert4_kernel<<<dim3(4096, 4), 256, 0, stream>>>(
        x, Wq, Wk, Wv, xb, Wqb, Wkb, Wvb);

    // fused QKV projection (192 GEMM blocks) + Wo convert (64 filler blocks)
    gemm256_qkv<<<dim3(8, 32), 512, 0, stream>>>(
        xb, Wqb, Wkb, Wvb, bq, bk, bv, Qb, Kb, Vtg, Wo, Wob);

    if (split) {
        // 2-way KV-split attention: 1024 blocks = exactly 4/CU resident
        attn_kernel<<<1024, 256, 0, stream>>>(Qb, Kb, Vtg, Op, Ls, Ab, 2);
        // merge partials + zero `out` (replaces hipMemsetAsync)
        merge_kernel<<<2048, 256, 0, stream>>>(Op, Ls, Ab, out);
        // out-projection: m97 128^2 K-split-2 (512 blocks = 2/CU),
        // atomicAdd into the out buffer zeroed by merge
        gemm_bt<float, 2><<<dim3(16, 32), 256, 0, stream>>>(
            Ab, Wob, Wob, Wob, bo, bo, bo, out, out, out, 16);
    } else {
        attn_kernel<<<512, 256, 0, stream>>>(Qb, Kb, Vtg, Op, Ls, Ab, 1);
        gemm_bt<float, 1><<<dim3(16, 16), 256, 0, stream>>>(
            Ab, Wob, Wob, Wob, bo, bo, bo, out, out, out, 16);
    }
}

// Round 11
// 291.756 us; speedup vs baseline: 1.3467x; 1.3467x over previous
//
#include <hip/hip_runtime.h>

#define SDIM 2048
#define EDIM 2048
#define NHEAD 16
#define DHEAD 128

typedef __attribute__((ext_vector_type(8))) short short8;
typedef __attribute__((ext_vector_type(4))) float floatx4;

__device__ __forceinline__ float bf2f(ushort u) {
    union { uint i; float f; } v; v.i = ((uint)u) << 16; return v.f;
}
__device__ __forceinline__ ushort f2bf(float f) {
    union { float f; uint i; } v; v.f = f;
    uint r = v.i + 0x7fff + ((v.i >> 16) & 1);
    return (ushort)(r >> 16);
}

// async global->LDS, 16B per lane. LDS dest = wave-uniform base + lane*16.
__device__ __forceinline__ void gload_lds16(const ushort* g, ushort* l) {
    __builtin_amdgcn_global_load_lds(
        (const __attribute__((address_space(1))) void*)g,
        (__attribute__((address_space(3))) void*)l, 16, 0, 0);
}

// ---------------- fused fp32 -> bf16 conversion (4 matrices; Wo is ----------
// converted inside the QKV launch on its idle CUs) ---------------------------
// NOTE (R7/R8 lesson): no fence-based in-kernel merge (per-XCD L2 writebacks
// serialize, ~200us). NOTE (R10 lesson): no reg-staged K/V prefetch in attn —
// the long live range across barriers makes hipcc demote the staging regs to
// scratch (WRITE_SIZE 41->355MB, attn 60->165us). Keep direct LDS staging.
__global__ void convert4_kernel(
    const float* __restrict__ s0, const float* __restrict__ s1,
    const float* __restrict__ s2, const float* __restrict__ s3,
    ushort* __restrict__ d0, ushort* __restrict__ d1,
    ushort* __restrict__ d2, ushort* __restrict__ d3)
{
    const float* src; ushort* dst;
    switch (blockIdx.y) {
        case 0: src = s0; dst = d0; break;
        case 1: src = s1; dst = d1; break;
        case 2: src = s2; dst = d2; break;
        default: src = s3; dst = d3; break;
    }
    int i = blockIdx.x * blockDim.x + threadIdx.x;
    float4 f = ((const float4*)src)[i];
    ushort4 o;
    o.x = f2bf(f.x); o.y = f2bf(f.y); o.z = f2bf(f.z); o.w = f2bf(f.w);
    ((ushort4*)dst)[i] = o;
}

#define QPRESCALE 0.12754245f   // (1/sqrt(128)) * log2(e)

// ======================================================================
// 256x256-tile deep-pipelined bf16 GEMM (C = A*B^T + bias), fused QKV.
// 8 waves (2M x 4N), BK=64, double-buffered 128 KiB LDS, counted vmcnt.
// 4 phases per K-tile, reads balanced 8/8/4/4 via kk-split. (R4's 3-phase
// merge REGRESSED in-profile — structure frozen at the R3 form.)
//   ph0: A-h0 kk0 + B kk0 (all 4 an) -> MFMA h0 x kk0
//   ph1: A-h0 kk1 + B kk1           -> MFMA h0 x kk1
//   ph2: A-h1 kk0 (B kk0 in regs)   -> MFMA h1 x kk0
//   ph3: A-h1 kk1 (B kk1 in regs)   -> MFMA h1 x kk1; vmcnt(4); barrier
// Staging: tile t stages A(t+1) in ph0/ph1, B(t+2) in ph2/ph3. vmcnt(4)
// at tile end keeps B(t+2) in flight; A(t+1)+B(t+1) proven landed.
// LDS XOR swizzle chunk^=(row&7) via pre-swizzled GLOBAL source
// (gload_lds writes linearly) + swizzled ds_read addr (both-sides rule).
// which: 0=Q (RoPE+QPRESCALE), 1=K (RoPE), 2=V (transposed Vt[h][d][s]).
// grid (8, 32): y in [24,32) = 64 filler blocks convert Wo fp32->bf16
// (192 GEMM + 64 convert = 256 blocks = 1/CU; Wo hidden under GEMM).
// ======================================================================
__global__ __launch_bounds__(512, 2) void gemm256_qkv(
    const ushort* __restrict__ A,
    const ushort* __restrict__ B0, const ushort* __restrict__ B1, const ushort* __restrict__ B2,
    const float* __restrict__ s0, const float* __restrict__ s1, const float* __restrict__ s2,
    ushort* __restrict__ C0, ushort* __restrict__ C1, ushort* __restrict__ Vtg,
    const float* __restrict__ WoF, ushort* __restrict__ WoB)
{
    // [buf][A=0/B=1][half][128 rows][64 k] bf16 = 128 KiB
    __shared__ __align__(16) ushort smem[2][2][2][128 * 64];

    const int tid  = threadIdx.x;

    if (blockIdx.y >= 24) {
        // ---- Wo conversion on the 64 filler blocks (no LDS, no barriers) ----
        const int idx = (blockIdx.y - 24) * 8 + blockIdx.x;   // [0,64)
        const float4* src = (const float4*)WoF;
#pragma unroll
        for (int it = 0; it < 32; ++it) {
            int i = idx * 16384 + it * 512 + tid;             // 64*16384*4 = 2048^2
            float4 f = src[i];
            ushort4 o;
            o.x = f2bf(f.x); o.y = f2bf(f.y); o.z = f2bf(f.z); o.w = f2bf(f.w);
            ((ushort4*)WoB)[i] = o;
        }
        return;
    }

    const int lane = tid & 63;
    const int wave = tid >> 6;
    const int l15 = lane & 15, quad = lane >> 4, l7 = lane & 7;
    const int wm = wave & 1, wn = wave >> 1;
    const int bm = blockIdx.x * 256;
    const int which = blockIdx.y >> 3;
    const int n0 = (blockIdx.y & 7) * 256;
    const int NT = EDIM / 64;   // 32

    const ushort* Bsel = (which == 0) ? B0 : (which == 1) ? B1 : B2;
    const float*  bia  = (which == 0) ? s0 : (which == 1) ? s1 : s2;

    // staging coords: thread covers rows (tid>>3) and (tid>>3)+64 of a
    // 128-row half, 16B chunk (tid&7); global chunk pre-swizzled by row&7.
    const int srow = tid >> 3;
    const int sgc  = (((tid & 7) ^ ((tid >> 3) & 7)) << 3); // ushorts

    floatx4 acc[8][4];
#pragma unroll
    for (int i = 0; i < 8; i++)
#pragma unroll
        for (int j = 0; j < 4; j++) acc[i][j] = (floatx4)0.0f;

    auto stageA = [&](int tile, int h) {
        const ushort* g = A + (size_t)(bm + h * 128 + srow) * EDIM + tile * 64 + sgc;
        ushort* l = &smem[tile & 1][0][h][0] + tid * 8;
        gload_lds16(g, l);
        gload_lds16(g + (size_t)64 * EDIM, l + 4096);
    };
    auto stageB = [&](int tile, int h) {
        const ushort* g = Bsel + (size_t)(n0 + h * 128 + srow) * EDIM + tile * 64 + sgc;
        ushort* l = &smem[tile & 1][1][h][0] + tid * 8;
        gload_lds16(g, l);
        gload_lds16(g + (size_t)64 * EDIM, l + 4096);
    };

    // prologue: tile 0 complete + B(1); drain through tile 0 (B(1) stays in flight)
    stageA(0, 0); stageA(0, 1); stageB(0, 0); stageB(0, 1);
    stageB(1, 0); stageB(1, 1);
    asm volatile("s_waitcnt vmcnt(4)" ::: "memory");
    __builtin_amdgcn_s_barrier();

    const int c0 = ((quad ^ l7) << 3);         // kk=0 swizzled chunk (ushorts)
    const int c1 = (((quad + 4) ^ l7) << 3);   // kk=1
    const int brow0 = (wn & 1) * 64;           // wave's B rows within its half

    short8 af[4], b0[4], b1[4];

#define MFMA16(AOFF, AF, BF) \
    _Pragma("unroll") \
    for (int mf = 0; mf < 4; mf++) \
        _Pragma("unroll") \
        for (int an = 0; an < 4; an++) \
            acc[(AOFF) + mf][an] = __builtin_amdgcn_mfma_f32_16x16x32_bf16( \
                AF[mf], BF[an], acc[(AOFF) + mf][an], 0, 0, 0);

#define PH_PRE() do { \
    asm volatile("" ::: "memory"); \
    __builtin_amdgcn_s_barrier(); \
    asm volatile("s_waitcnt lgkmcnt(0)" ::: "memory"); \
    __builtin_amdgcn_sched_barrier(0); \
    __builtin_amdgcn_s_setprio(1); \
} while (0)
#define PH_POST() do { \
    __builtin_amdgcn_s_setprio(0); \
    asm volatile("" ::: "memory"); \
    __builtin_amdgcn_s_barrier(); \
} while (0)

    for (int t = 0; t < NT; ++t) {
        const ushort* aH = &smem[t & 1][0][wm][0];
        const ushort* bH = &smem[t & 1][1][wn >> 1][0];

        // ---- phase 0: read A-h0 kk0 (4) + B kk0 (4); stage A(t+1,h0); MFMA h0 x kk0
#pragma unroll
        for (int mf = 0; mf < 4; mf++)
            af[mf] = *(const short8*)(aH + (mf * 16 + l15) * 64 + c0);
#pragma unroll
        for (int an = 0; an < 4; an++)
            b0[an] = *(const short8*)(bH + (brow0 + an * 16 + l15) * 64 + c0);
        if (t + 1 < NT) stageA(t + 1, 0);
        PH_PRE();
        MFMA16(0, af, b0);
        PH_POST();

        // ---- phase 1: read A-h0 kk1 (4) + B kk1 (4); stage A(t+1,h1); MFMA h0 x kk1
        short8 ag[4];
#pragma unroll
        for (int mf = 0; mf < 4; mf++)
            ag[mf] = *(const short8*)(aH + (mf * 16 + l15) * 64 + c1);
#pragma unroll
        for (int an = 0; an < 4; an++)
            b1[an] = *(const short8*)(bH + (brow0 + an * 16 + l15) * 64 + c1);
        if (t + 1 < NT) stageA(t + 1, 1);
        PH_PRE();
        MFMA16(0, ag, b1);
        PH_POST();

        // ---- phase 2: read A-h1 kk0 (4); stage B(t+2,h0); MFMA h1 x kk0
#pragma unroll
        for (int mf = 0; mf < 4; mf++)
            af[mf] = *(const short8*)(aH + (64 + mf * 16 + l15) * 64 + c0);
        if (t + 2 < NT) stageB(t + 2, 0);
        PH_PRE();
        MFMA16(4, af, b0);
        PH_POST();

        // ---- phase 3: read A-h1 kk1 (4); stage B(t+2,h1); MFMA h1 x kk1; vmcnt
#pragma unroll
        for (int mf = 0; mf < 4; mf++)
            ag[mf] = *(const short8*)(aH + (64 + mf * 16 + l15) * 64 + c1);
        if (t + 2 < NT) stageB(t + 2, 1);
        asm volatile("" ::: "memory");
        __builtin_amdgcn_s_barrier();
        asm volatile("s_waitcnt lgkmcnt(0)" ::: "memory");
        __builtin_amdgcn_sched_barrier(0);
        __builtin_amdgcn_s_setprio(1);
        MFMA16(4, ag, b1);
        __builtin_amdgcn_s_setprio(0);
        if (t < NT - 2) asm volatile("s_waitcnt vmcnt(4)" ::: "memory");
        else            asm volatile("s_waitcnt vmcnt(0)" ::: "memory");
        __builtin_amdgcn_s_barrier();
    }
#undef MFMA16
#undef PH_PRE
#undef PH_POST

    // ---------------- epilogues (all gloads drained by tail vmcnt(0)) ----------
    if (which == 2) {
        // V: transposed write Vt[h][d][s], 4 consecutive s packed per store
#pragma unroll
        for (int an = 0; an < 4; an++) {
            int col = n0 + wn * 64 + an * 16 + l15;
            int h = col >> 7, d = col & 127;
            float bv = bia[col];
            ushort* cp = Vtg + (size_t)h * SDIM * DHEAD + (size_t)d * SDIM;
#pragma unroll
            for (int am = 0; am < 8; am++) {
                int s = bm + wm * 128 + am * 16 + quad * 4;
                ushort4 pk;
                pk.x = f2bf(acc[am][an][0] + bv);
                pk.y = f2bf(acc[am][an][1] + bv);
                pk.z = f2bf(acc[am][an][2] + bv);
                pk.w = f2bf(acc[am][an][3] + bv);
                *(ushort4*)(cp + s) = pk;
            }
        }
    } else {
        // Q/K: fused RoPE. Pair (d, d+64) lives in partner wave (wave^2,
        // same wm, wn bit0 flipped = +-64 cols). Exchange via dead staging
        // LDS, TWO am-slices per barrier pair (64 KB of the 128 KB buffer).
        ushort* C = (which == 0) ? C0 : C1;
        const float psc = (which == 0) ? QPRESCALE : 1.0f;
        float* xch = (float*)smem;
        float bv[4], invf[4];
#pragma unroll
        for (int an = 0; an < 4; an++) {
            bv[an]   = bia[n0 + wn * 64 + an * 16 + l15];
            invf[an] = __expf((float)(an * 16 + l15) * -0.14391157f);  // 10000^(-i/64)
        }
        const int mybase = wave * 1024 + quad * 16 + l15;
        const int pbase  = (wave ^ 2) * 1024 + quad * 16 + l15;
        const int rowb = bm + wm * 128 + quad * 4;
#pragma unroll
        for (int am2 = 0; am2 < 4; am2++) {
            __syncthreads();
#pragma unroll
            for (int sl = 0; sl < 2; sl++) {
                int am = am2 * 2 + sl;
#pragma unroll
                for (int an = 0; an < 4; an++)
#pragma unroll
                    for (int r = 0; r < 4; r++)
                        xch[sl * 8192 + mybase + an * 256 + r * 64] = acc[am][an][r] + bv[an];
            }
            __syncthreads();
#pragma unroll
            for (int sl = 0; sl < 2; sl++) {
                int am = am2 * 2 + sl;
#pragma unroll
                for (int an = 0; an < 4; an++) {
                    int col = n0 + wn * 64 + an * 16 + l15;
#pragma unroll
                    for (int r = 0; r < 4; r++) {
                        int row = rowb + am * 16 + r;
                        float v = acc[am][an][r] + bv[an];
                        float w = xch[sl * 8192 + pbase + an * 256 + r * 64];
                        float ang = (float)row * invf[an];
                        float rev = ang * 0.15915494309f;
                        rev -= floorf(rev);
                        float arad = rev * 6.28318530718f;
                        float sn = __sinf(arad), cs = __cosf(arad);
                        float o = ((wn & 1) == 0) ? (v * cs - w * sn) : (v * cs + w * sn);
                        C[(size_t)row * EDIM + col] = f2bf(o * psc);
                    }
                }
            }
        }
    }
}

// ---------------- bf16 GEMM: C = A * B^T + bias (m97 structure) ----------------
// Used for the output projection (KSPLIT=2, 512 blocks = 2/CU) and the
// no-split fallback.
template <typename OUTT, int KSPLIT>
__global__ __launch_bounds__(256) void gemm_bt(
    const ushort* __restrict__ A,
    const ushort* __restrict__ B0, const ushort* __restrict__ B1, const ushort* __restrict__ B2,
    const float* __restrict__ s0, const float* __restrict__ s1, const float* __restrict__ s2,
    OUTT* __restrict__ C0, OUTT* __restrict__ C1, OUTT* __restrict__ C2,
    int nbpm)
{
    __shared__ __align__(16) ushort smem[2 * 128 * 32];
    ushort* a_s = smem;
    ushort* b_s = smem + 128 * 32;

    const int tid = threadIdx.x;
    const int wave = tid >> 6, lane = tid & 63;
    const int l15 = lane & 15, quad = lane >> 4;
    const int wm = wave & 1, wn = wave >> 1;
    const int bm = blockIdx.x * 128;
    const int which = blockIdx.y / nbpm;
    const int n0 = (blockIdx.y % nbpm) * 128;

    const ushort* B;
    const float*  bia;
    OUTT*         C;
    const ushort* Abase;
    if constexpr (KSPLIT == 2) {
        B = B0; bia = s0; C = C0;
        Abase = A + which * (EDIM / 2);
    } else {
        B   = (which == 0) ? B0 : (which == 1) ? B1 : B2;
        bia = (which == 0) ? s0 : (which == 1) ? s1 : s2;
        C   = (which == 0) ? C0 : (which == 1) ? C1 : C2;
        Abase = A;
    }
    const ushort* Bbase = (KSPLIT == 2) ? B + which * (EDIM / 2) : B;

    floatx4 acc[4][4];
#pragma unroll
    for (int i = 0; i < 4; i++)
#pragma unroll
        for (int j = 0; j < 4; j++) acc[i][j] = (floatx4)0.0f;

    const int t1 = tid + 256;
    const int row0 = tid >> 2, kc0 = (tid & 3) * 8;
    const int row1 = t1 >> 2,  kc1 = (t1 & 3) * 8;

    for (int k0 = 0; k0 < EDIM / KSPLIT; k0 += 32) {
        __syncthreads();
        gload_lds16(Abase + (size_t)(bm + row0) * EDIM + k0 + kc0, a_s + tid * 8);
        gload_lds16(Abase + (size_t)(bm + row1) * EDIM + k0 + kc1, a_s + t1 * 8);
        gload_lds16(Bbase + (size_t)(n0 + row0) * EDIM + k0 + kc0, b_s + tid * 8);
        gload_lds16(Bbase + (size_t)(n0 + row1) * EDIM + k0 + kc1, b_s + t1 * 8);
        __syncthreads();

        short8 af[4], bf[4];
#pragma unroll
        for (int mt = 0; mt < 4; mt++)
            af[mt] = *(const short8*)(a_s + (wm * 64 + mt * 16 + l15) * 32 + quad * 8);
#pragma unroll
        for (int nt = 0; nt < 4; nt++)
            bf[nt] = *(const short8*)(b_s + (wn * 64 + nt * 16 + l15) * 32 + quad * 8);
#pragma unroll
        for (int mt = 0; mt < 4; mt++)
#pragma unroll
            for (int nt = 0; nt < 4; nt++)
                acc[mt][nt] = __builtin_amdgcn_mfma_f32_16x16x32_bf16(af[mt], bf[nt], acc[mt][nt], 0, 0, 0);
    }

    if constexpr (KSPLIT == 2) {
#pragma unroll
        for (int nt = 0; nt < 4; nt++) {
            int col = n0 + wn * 64 + nt * 16 + l15;
            float bv = (which == 0) ? bia[col] : 0.0f;
#pragma unroll
            for (int mt = 0; mt < 4; mt++) {
#pragma unroll
                for (int r = 0; r < 4; r++) {
                    int row = bm + wm * 64 + mt * 16 + quad * 4 + r;
                    atomicAdd(&((float*)C)[(size_t)row * EDIM + col], acc[mt][nt][r] + bv);
                }
            }
        }
    } else {
#pragma unroll
        for (int nt = 0; nt < 4; nt++) {
            int col = n0 + wn * 64 + nt * 16 + l15;
            float bv = bia[col];
#pragma unroll
            for (int mt = 0; mt < 4; mt++) {
#pragma unroll
                for (int r = 0; r < 4; r++) {
                    int row = bm + wm * 64 + mt * 16 + quad * 4 + r;
                    float v = acc[mt][nt][r] + bv;
                    if constexpr (sizeof(OUTT) == 2)
                        ((ushort*)C)[(size_t)row * EDIM + col] = f2bf(v);
                    else
                        ((float*)C)[(size_t)row * EDIM + col] = v;
                }
            }
        }
    }
}

// ---------------- flash attention: S^T trick + fixed-max softmax ----------------
// s_setprio around MFMA clusters (T5). nsplit=2: grid 1024 = 4 blocks/CU
// (LDS exactly 40960 B — do not add any __shared__ bytes; +512 B drops to
// 3 blocks/CU and ~3x the runtime, R7). Direct uint4 global->LDS staging
// (R10 lesson: reg-held prefetch across barriers spills to scratch).
#define MFIX2 17.31234049f   // 12 * log2(e)
__global__ __launch_bounds__(256, 4) void attn_kernel(
    const ushort* __restrict__ Q, const ushort* __restrict__ K,
    const ushort* __restrict__ Vtg,
    ushort* __restrict__ Opart, float* __restrict__ Lsum,
    ushort* __restrict__ Ab, int nsplit)
{
    __shared__ __align__(16) ushort Ks[64 * 128];
    __shared__ __align__(16) ushort Vt[128 * 64];
    __shared__ __align__(16) ushort Ps[64 * 64];

    const int bid = blockIdx.x;
    const int head = bid & 15, qt = (bid >> 4) & 31, half = bid >> 9;
    const int tid = threadIdx.x, wave = tid >> 6, lane = tid & 63;
    const int l15 = lane & 15, quad = lane >> 4;
    const int l7 = l15 & 7;
    const int kstart = half * (SDIM / nsplit);
    const int ntile = (SDIM / nsplit) / 64;

    short8 qf[4];
    {
        int s = qt * 64 + wave * 16 + l15;
        const ushort* qp = Q + (size_t)s * EDIM + head * DHEAD;
#pragma unroll
        for (int kc = 0; kc < 4; kc++) qf[kc] = *(const short8*)(qp + kc * 32 + quad * 8);
    }

    floatx4 o[8];
#pragma unroll
    for (int i = 0; i < 8; i++) o[i] = (floatx4)0.0f;
    float lsum = 0.0f;

    const int krow = tid >> 4, kc8 = tid & 15;
    const int vd = tid >> 3, vc8 = tid & 7;
    const int prow = wave * 16 + l15;

    for (int kv = 0; kv < ntile; kv++) {
        const int k0 = kstart + kv * 64;
        __syncthreads();
#pragma unroll
        for (int i = 0; i < 4; i++) {
            int row = krow + i * 16;
            uint4 v = *(const uint4*)(K + (size_t)(k0 + row) * EDIM + head * DHEAD + kc8 * 8);
            *(uint4*)(Ks + row * 128 + ((kc8 ^ (row & 7)) << 3)) = v;
        }
#pragma unroll
        for (int i = 0; i < 4; i++) {
            int d = vd + i * 32;
            uint4 v = *(const uint4*)(Vtg + (size_t)head * SDIM * DHEAD + (size_t)d * SDIM + k0 + vc8 * 8);
            *(uint4*)(Vt + d * 64 + ((vc8 ^ (d & 7)) << 3)) = v;
        }
        __syncthreads();

#pragma unroll
        for (int nt = 0; nt < 4; nt++) {
            floatx4 st = (floatx4)0.0f;
            __builtin_amdgcn_s_setprio(1);
#pragma unroll
            for (int kc = 0; kc < 4; kc++) {
                short8 kfr = *(const short8*)(Ks + (nt * 16 + l15) * 128 + (((kc * 4 + quad) ^ l7) << 3));
                st = __builtin_amdgcn_mfma_f32_16x16x32_bf16(kfr, qf[kc], st, 0, 0, 0);
            }
            __builtin_amdgcn_s_setprio(0);
            ushort4 pk;
            float p0 = __builtin_amdgcn_exp2f(st[0] - MFIX2);
            float p1 = __builtin_amdgcn_exp2f(st[1] - MFIX2);
            float p2 = __builtin_amdgcn_exp2f(st[2] - MFIX2);
            float p3 = __builtin_amdgcn_exp2f(st[3] - MFIX2);
            lsum += (p0 + p1) + (p2 + p3);
            pk.x = f2bf(p0); pk.y = f2bf(p1); pk.z = f2bf(p2); pk.w = f2bf(p3);
            int c2 = (nt * 2 + (quad >> 1)) ^ l7;
            *(ushort4*)(Ps + prow * 64 + (c2 << 3) + ((quad & 1) << 2)) = pk;
        }

        __builtin_amdgcn_s_setprio(1);
#pragma unroll
        for (int kc2 = 0; kc2 < 2; kc2++) {
            short8 af = *(const short8*)(Ps + prow * 64 + (((kc2 * 4 + quad) ^ l7) << 3));
#pragma unroll
            for (int nt2 = 0; nt2 < 8; nt2++) {
                short8 bfr = *(const short8*)(Vt + (nt2 * 16 + l15) * 64 + (((kc2 * 4 + quad) ^ l7) << 3));
                o[nt2] = __builtin_amdgcn_mfma_f32_16x16x32_bf16(af, bfr, o[nt2], 0, 0, 0);
            }
        }
        __builtin_amdgcn_s_setprio(0);
    }

    lsum += __shfl_xor(lsum, 16);
    lsum += __shfl_xor(lsum, 32);

    if (nsplit == 1) {
        float invl[4];
#pragma unroll
        for (int r = 0; r < 4; r++) invl[r] = 1.0f / __shfl(lsum, quad * 4 + r, 16);
#pragma unroll
        for (int nt2 = 0; nt2 < 8; nt2++) {
#pragma unroll
            for (int r = 0; r < 4; r++) {
                int s = qt * 64 + wave * 16 + quad * 4 + r;
                int d = nt2 * 16 + l15;
                Ab[(size_t)head * SDIM * DHEAD + (size_t)s * DHEAD + d] = f2bf(o[nt2][r] * invl[r]);
            }
        }
    } else {
        size_t pb = ((size_t)half * NHEAD + head) * SDIM * DHEAD;
#pragma unroll
        for (int nt2 = 0; nt2 < 8; nt2++) {
#pragma unroll
            for (int r = 0; r < 4; r++) {
                int s = qt * 64 + wave * 16 + quad * 4 + r;
                int d = nt2 * 16 + l15;
                Opart[pb + (size_t)s * DHEAD + d] = f2bf(o[nt2][r]);
            }
        }
        if (lane < 16)
            Lsum[((size_t)half * NHEAD + head) * SDIM + qt * 64 + wave * 16 + lane] = lsum;
    }
}

// ---------------- merge two KV-split partials (shared fixed max) ----------------
// Also zeroes `out` (2 float4/thread = 16MB over 2048 blocks) — replaces
// the hipMemsetAsync dispatch; stream order still puts all zeroing before
// the out-projection's atomics.
__global__ void merge_kernel(const ushort* __restrict__ Opart,
                             const float* __restrict__ Lsum,
                             ushort* __restrict__ Ab,
                             float* __restrict__ outz)
{
    const int HS = NHEAD * SDIM;
    int t = blockIdx.x * blockDim.x + threadIdx.x;

    // zero out: 2048*256 threads x 2 float4 = 4M floats = 16MB
    float4 z = {0.f, 0.f, 0.f, 0.f};
    ((float4*)outz)[t] = z;
    ((float4*)outz)[t + 524288] = z;

    int row = t >> 4, c8 = (t & 15) * 8;
    float inv = 1.0f / (Lsum[row] + Lsum[HS + row]);
    float acc[8] = {0, 0, 0, 0, 0, 0, 0, 0};
#pragma unroll
    for (int p = 0; p < 2; p++) {
        union { uint4 v; ushort u[8]; } a;
        a.v = *(const uint4*)(Opart + (size_t)p * HS * DHEAD + (size_t)row * DHEAD + c8);
#pragma unroll
        for (int j = 0; j < 8; j++) acc[j] += bf2f(a.u[j]);
    }
    union { uint4 v; ushort u[8]; } ro;
#pragma unroll
    for (int j = 0; j < 8; j++) ro.u[j] = f2bf(acc[j] * inv);
    *(uint4*)(Ab + (size_t)row * DHEAD + c8) = ro.v;
}

extern "C" void kernel_launch(void* const* d_in, const int* in_sizes, int n_in,
                              void* d_out, int out_size, void* d_ws, size_t ws_size,
                              hipStream_t stream) {
    (void)in_sizes; (void)n_in; (void)out_size;
    const float* x  = (const float*)d_in[0];
    const float* Wq = (const float*)d_in[1];
    const float* bq = (const float*)d_in[2];
    const float* Wk = (const float*)d_in[3];
    const float* bk = (const float*)d_in[4];
    const float* Wv = (const float*)d_in[5];
    const float* bv = (const float*)d_in[6];
    const float* Wo = (const float*)d_in[7];
    const float* bo = (const float*)d_in[8];
    float* out = (float*)d_out;

    char* ws = (char*)d_ws;
    const size_t SEG = (size_t)EDIM * EDIM * 2;  // 8 MB per bf16 matrix
    ushort* xb  = (ushort*)(ws + 0 * SEG);
    ushort* Wqb = (ushort*)(ws + 1 * SEG);
    ushort* Wkb = (ushort*)(ws + 2 * SEG);
    ushort* Wvb = (ushort*)(ws + 3 * SEG);
    ushort* Wob = (ushort*)(ws + 4 * SEG);
    ushort* Qb  = (ushort*)(ws + 5 * SEG);
    ushort* Kb  = (ushort*)(ws + 6 * SEG);
    ushort* Vtg = (ushort*)(ws + 7 * SEG);   // V pre-transposed [h][d][s]
    ushort* Ab  = (ushort*)(ws + 8 * SEG);
    ushort* Op  = (ushort*)(ws + 0 * SEG);   // attn partials reuse SEG0-1 (2 x 8MB)
    float*  Ls  = (float*)(ws + 11 * SEG);   // 2 x 32768 x 4B = 256KB

    const int split = (ws_size >= ((size_t)89 << 20)) ? 1 : 0;

    // x, Wq, Wk, Wv converted up front; Wo converted inside the QKV launch
    convert4_kernel<<<dim3(4096, 4), 256, 0, stream>>>(
        x, Wq, Wk, Wv, xb, Wqb, Wkb, Wvb);

    // fused QKV projection (192 GEMM blocks) + Wo convert (64 filler blocks)
    gemm256_qkv<<<dim3(8, 32), 512, 0, stream>>>(
        xb, Wqb, Wkb, Wvb, bq, bk, bv, Qb, Kb, Vtg, Wo, Wob);

    if (split) {
        // 2-way KV-split attention: 1024 blocks = exactly 4/CU resident
        attn_kernel<<<1024, 256, 0, stream>>>(Qb, Kb, Vtg, Op, Ls, Ab, 2);
        // merge partials + zero `out` (replaces hipMemsetAsync)
        merge_kernel<<<2048, 256, 0, stream>>>(Op, Ls, Ab, out);
        // out-projection: m97 128^2 K-split-2 (512 blocks = 2/CU),
        // atomicAdd into the out buffer zeroed by merge
        gemm_bt<float, 2><<<dim3(16, 32), 256, 0, stream>>>(
            Ab, Wob, Wob, Wob, bo, bo, bo, out, out, out, 16);
    } else {
        attn_kernel<<<512, 256, 0, stream>>>(Qb, Kb, Vtg, Op, Ls, Ab, 1);
        gemm_bt<float, 1><<<dim3(16, 16), 256, 0, stream>>>(
            Ab, Wob, Wob, Wob, bo, bo, bo, out, out, out, 16);
    }
}

// Round 12
// 285.894 us; speedup vs baseline: 1.3743x; 1.0205x over previous
//
#include <hip/hip_runtime.h>

#define SDIM 2048
#define EDIM 2048
#define NHEAD 16
#define DHEAD 128

typedef __attribute__((ext_vector_type(8))) short short8;
typedef __attribute__((ext_vector_type(4))) float floatx4;

__device__ __forceinline__ float bf2f(ushort u) {
    union { uint i; float f; } v; v.i = ((uint)u) << 16; return v.f;
}
__device__ __forceinline__ ushort f2bf(float f) {
    union { float f; uint i; } v; v.f = f;
    uint r = v.i + 0x7fff + ((v.i >> 16) & 1);
    return (ushort)(r >> 16);
}

// async global->LDS, 16B per lane. LDS dest = wave-uniform base + lane*16.
__device__ __forceinline__ void gload_lds16(const ushort* g, ushort* l) {
    __builtin_amdgcn_global_load_lds(
        (const __attribute__((address_space(1))) void*)g,
        (__attribute__((address_space(3))) void*)l, 16, 0, 0);
}

// ---------------- fused fp32 -> bf16 conversion (4 matrices; Wo is ----------
// converted inside the QKV launch on its idle CUs) ---------------------------
// LESSONS LEDGER: (R7/R8) no fence-based in-kernel merge — per-XCD L2
// writebacks serialize (~200us). (R10) no reg-staged K/V prefetch across
// barriers in attn — hipcc demotes to scratch (WRITE 41->355MB). (R4) no
// QKV phase merging. (R7) attn LDS must stay exactly 40960 B.
// R12: grid-stride 8 float4/thread (2048 blocks, was 16384 x 1).
__global__ void convert4_kernel(
    const float* __restrict__ s0, const float* __restrict__ s1,
    const float* __restrict__ s2, const float* __restrict__ s3,
    ushort* __restrict__ d0, ushort* __restrict__ d1,
    ushort* __restrict__ d2, ushort* __restrict__ d3)
{
    const float* src; ushort* dst;
    switch (blockIdx.y) {
        case 0: src = s0; dst = d0; break;
        case 1: src = s1; dst = d1; break;
        case 2: src = s2; dst = d2; break;
        default: src = s3; dst = d3; break;
    }
    const int base = blockIdx.x * 2048 + threadIdx.x;
#pragma unroll
    for (int j = 0; j < 8; ++j) {
        int i = base + j * 256;
        float4 f = ((const float4*)src)[i];
        ushort4 o;
        o.x = f2bf(f.x); o.y = f2bf(f.y); o.z = f2bf(f.z); o.w = f2bf(f.w);
        ((ushort4*)dst)[i] = o;
    }
}

#define QPRESCALE 0.12754245f   // (1/sqrt(128)) * log2(e)

// ======================================================================
// 256x256-tile deep-pipelined bf16 GEMM (C = A*B^T + bias), fused QKV.
// 8 waves (2M x 4N), BK=64, double-buffered 128 KiB LDS, counted vmcnt.
// 4 phases per K-tile, reads balanced 8/8/4/4 via kk-split (frozen).
//   ph0: A-h0 kk0 + B kk0 (all 4 an) -> MFMA h0 x kk0
//   ph1: A-h0 kk1 + B kk1           -> MFMA h0 x kk1
//   ph2: A-h1 kk0 (B kk0 in regs)   -> MFMA h1 x kk0
//   ph3: A-h1 kk1 (B kk1 in regs)   -> MFMA h1 x kk1; vmcnt(4); barrier
// Staging: tile t stages A(t+1) in ph0/ph1, B(t+2) in ph2/ph3. vmcnt(4)
// at tile end keeps B(t+2) in flight; A(t+1)+B(t+1) proven landed.
// LDS XOR swizzle chunk^=(row&7) via pre-swizzled GLOBAL source
// (gload_lds writes linearly) + swizzled ds_read addr (both-sides rule).
// which: 0=Q (RoPE+QPRESCALE), 1=K (RoPE), 2=V (transposed Vt[h][d][s]).
// grid (8, 32): y in [24,32) = 64 filler blocks convert Wo fp32->bf16
// AND zero `out` (R12; both hidden under the ~70us GEMM window; zeroing
// is stream-ordered before the out-projection's atomics).
// ======================================================================
__global__ __launch_bounds__(512, 2) void gemm256_qkv(
    const ushort* __restrict__ A,
    const ushort* __restrict__ B0, const ushort* __restrict__ B1, const ushort* __restrict__ B2,
    const float* __restrict__ s0, const float* __restrict__ s1, const float* __restrict__ s2,
    ushort* __restrict__ C0, ushort* __restrict__ C1, ushort* __restrict__ Vtg,
    const float* __restrict__ WoF, ushort* __restrict__ WoB,
    float* __restrict__ outz)
{
    // [buf][A=0/B=1][half][128 rows][64 k] bf16 = 128 KiB
    __shared__ __align__(16) ushort smem[2][2][2][128 * 64];

    const int tid  = threadIdx.x;

    if (blockIdx.y >= 24) {
        // ---- filler blocks: Wo convert + out zero (no LDS, no barriers) ----
        const int idx = (blockIdx.y - 24) * 8 + blockIdx.x;   // [0,64)
        const float4* src = (const float4*)WoF;
#pragma unroll
        for (int it = 0; it < 32; ++it) {
            int i = idx * 16384 + it * 512 + tid;             // 64*16384*4 = 2048^2
            float4 f = src[i];
            ushort4 o;
            o.x = f2bf(f.x); o.y = f2bf(f.y); o.z = f2bf(f.z); o.w = f2bf(f.w);
            ((ushort4*)WoB)[i] = o;
        }
        float4 z = {0.f, 0.f, 0.f, 0.f};
        float4* oz = (float4*)outz;
#pragma unroll
        for (int it = 0; it < 32; ++it)
            oz[idx * 16384 + it * 512 + tid] = z;
        return;
    }

    const int lane = tid & 63;
    const int wave = tid >> 6;
    const int l15 = lane & 15, quad = lane >> 4, l7 = lane & 7;
    const int wm = wave & 1, wn = wave >> 1;
    const int bm = blockIdx.x * 256;
    const int which = blockIdx.y >> 3;
    const int n0 = (blockIdx.y & 7) * 256;
    const int NT = EDIM / 64;   // 32

    const ushort* Bsel = (which == 0) ? B0 : (which == 1) ? B1 : B2;
    const float*  bia  = (which == 0) ? s0 : (which == 1) ? s1 : s2;

    // staging coords: thread covers rows (tid>>3) and (tid>>3)+64 of a
    // 128-row half, 16B chunk (tid&7); global chunk pre-swizzled by row&7.
    const int srow = tid >> 3;
    const int sgc  = (((tid & 7) ^ ((tid >> 3) & 7)) << 3); // ushorts

    floatx4 acc[8][4];
#pragma unroll
    for (int i = 0; i < 8; i++)
#pragma unroll
        for (int j = 0; j < 4; j++) acc[i][j] = (floatx4)0.0f;

    auto stageA = [&](int tile, int h) {
        const ushort* g = A + (size_t)(bm + h * 128 + srow) * EDIM + tile * 64 + sgc;
        ushort* l = &smem[tile & 1][0][h][0] + tid * 8;
        gload_lds16(g, l);
        gload_lds16(g + (size_t)64 * EDIM, l + 4096);
    };
    auto stageB = [&](int tile, int h) {
        const ushort* g = Bsel + (size_t)(n0 + h * 128 + srow) * EDIM + tile * 64 + sgc;
        ushort* l = &smem[tile & 1][1][h][0] + tid * 8;
        gload_lds16(g, l);
        gload_lds16(g + (size_t)64 * EDIM, l + 4096);
    };

    // prologue: tile 0 complete + B(1); drain through tile 0 (B(1) stays in flight)
    stageA(0, 0); stageA(0, 1); stageB(0, 0); stageB(0, 1);
    stageB(1, 0); stageB(1, 1);
    asm volatile("s_waitcnt vmcnt(4)" ::: "memory");
    __builtin_amdgcn_s_barrier();

    const int c0 = ((quad ^ l7) << 3);         // kk=0 swizzled chunk (ushorts)
    const int c1 = (((quad + 4) ^ l7) << 3);   // kk=1
    const int brow0 = (wn & 1) * 64;           // wave's B rows within its half

    short8 af[4], b0[4], b1[4];

#define MFMA16(AOFF, AF, BF) \
    _Pragma("unroll") \
    for (int mf = 0; mf < 4; mf++) \
        _Pragma("unroll") \
        for (int an = 0; an < 4; an++) \
            acc[(AOFF) + mf][an] = __builtin_amdgcn_mfma_f32_16x16x32_bf16( \
                AF[mf], BF[an], acc[(AOFF) + mf][an], 0, 0, 0);

#define PH_PRE() do { \
    asm volatile("" ::: "memory"); \
    __builtin_amdgcn_s_barrier(); \
    asm volatile("s_waitcnt lgkmcnt(0)" ::: "memory"); \
    __builtin_amdgcn_sched_barrier(0); \
    __builtin_amdgcn_s_setprio(1); \
} while (0)
#define PH_POST() do { \
    __builtin_amdgcn_s_setprio(0); \
    asm volatile("" ::: "memory"); \
    __builtin_amdgcn_s_barrier(); \
} while (0)

    for (int t = 0; t < NT; ++t) {
        const ushort* aH = &smem[t & 1][0][wm][0];
        const ushort* bH = &smem[t & 1][1][wn >> 1][0];

        // ---- phase 0: read A-h0 kk0 (4) + B kk0 (4); stage A(t+1,h0); MFMA h0 x kk0
#pragma unroll
        for (int mf = 0; mf < 4; mf++)
            af[mf] = *(const short8*)(aH + (mf * 16 + l15) * 64 + c0);
#pragma unroll
        for (int an = 0; an < 4; an++)
            b0[an] = *(const short8*)(bH + (brow0 + an * 16 + l15) * 64 + c0);
        if (t + 1 < NT) stageA(t + 1, 0);
        PH_PRE();
        MFMA16(0, af, b0);
        PH_POST();

        // ---- phase 1: read A-h0 kk1 (4) + B kk1 (4); stage A(t+1,h1); MFMA h0 x kk1
        short8 ag[4];
#pragma unroll
        for (int mf = 0; mf < 4; mf++)
            ag[mf] = *(const short8*)(aH + (mf * 16 + l15) * 64 + c1);
#pragma unroll
        for (int an = 0; an < 4; an++)
            b1[an] = *(const short8*)(bH + (brow0 + an * 16 + l15) * 64 + c1);
        if (t + 1 < NT) stageA(t + 1, 1);
        PH_PRE();
        MFMA16(0, ag, b1);
        PH_POST();

        // ---- phase 2: read A-h1 kk0 (4); stage B(t+2,h0); MFMA h1 x kk0
#pragma unroll
        for (int mf = 0; mf < 4; mf++)
            af[mf] = *(const short8*)(aH + (64 + mf * 16 + l15) * 64 + c0);
        if (t + 2 < NT) stageB(t + 2, 0);
        PH_PRE();
        MFMA16(4, af, b0);
        PH_POST();

        // ---- phase 3: read A-h1 kk1 (4); stage B(t+2,h1); MFMA h1 x kk1; vmcnt
#pragma unroll
        for (int mf = 0; mf < 4; mf++)
            ag[mf] = *(const short8*)(aH + (64 + mf * 16 + l15) * 64 + c1);
        if (t + 2 < NT) stageB(t + 2, 1);
        asm volatile("" ::: "memory");
        __builtin_amdgcn_s_barrier();
        asm volatile("s_waitcnt lgkmcnt(0)" ::: "memory");
        __builtin_amdgcn_sched_barrier(0);
        __builtin_amdgcn_s_setprio(1);
        MFMA16(4, ag, b1);
        __builtin_amdgcn_s_setprio(0);
        if (t < NT - 2) asm volatile("s_waitcnt vmcnt(4)" ::: "memory");
        else            asm volatile("s_waitcnt vmcnt(0)" ::: "memory");
        __builtin_amdgcn_s_barrier();
    }
#undef MFMA16
#undef PH_PRE
#undef PH_POST

    // ---------------- epilogues (all gloads drained by tail vmcnt(0)) ----------
    if (which == 2) {
        // V: transposed write Vt[h][d][s], 4 consecutive s packed per store
#pragma unroll
        for (int an = 0; an < 4; an++) {
            int col = n0 + wn * 64 + an * 16 + l15;
            int h = col >> 7, d = col & 127;
            float bv = bia[col];
            ushort* cp = Vtg + (size_t)h * SDIM * DHEAD + (size_t)d * SDIM;
#pragma unroll
            for (int am = 0; am < 8; am++) {
                int s = bm + wm * 128 + am * 16 + quad * 4;
                ushort4 pk;
                pk.x = f2bf(acc[am][an][0] + bv);
                pk.y = f2bf(acc[am][an][1] + bv);
                pk.z = f2bf(acc[am][an][2] + bv);
                pk.w = f2bf(acc[am][an][3] + bv);
                *(ushort4*)(cp + s) = pk;
            }
        }
    } else {
        // Q/K: fused RoPE. Pair (d, d+64) lives in partner wave (wave^2,
        // same wm, wn bit0 flipped = +-64 cols). Exchange via dead staging
        // LDS, TWO am-slices per barrier pair (64 KB of the 128 KB buffer).
        ushort* C = (which == 0) ? C0 : C1;
        const float psc = (which == 0) ? QPRESCALE : 1.0f;
        float* xch = (float*)smem;
        float bv[4], invf[4];
#pragma unroll
        for (int an = 0; an < 4; an++) {
            bv[an]   = bia[n0 + wn * 64 + an * 16 + l15];
            invf[an] = __expf((float)(an * 16 + l15) * -0.14391157f);  // 10000^(-i/64)
        }
        const int mybase = wave * 1024 + quad * 16 + l15;
        const int pbase  = (wave ^ 2) * 1024 + quad * 16 + l15;
        const int rowb = bm + wm * 128 + quad * 4;
#pragma unroll
        for (int am2 = 0; am2 < 4; am2++) {
            __syncthreads();
#pragma unroll
            for (int sl = 0; sl < 2; sl++) {
                int am = am2 * 2 + sl;
#pragma unroll
                for (int an = 0; an < 4; an++)
#pragma unroll
                    for (int r = 0; r < 4; r++)
                        xch[sl * 8192 + mybase + an * 256 + r * 64] = acc[am][an][r] + bv[an];
            }
            __syncthreads();
#pragma unroll
            for (int sl = 0; sl < 2; sl++) {
                int am = am2 * 2 + sl;
#pragma unroll
                for (int an = 0; an < 4; an++) {
                    int col = n0 + wn * 64 + an * 16 + l15;
#pragma unroll
                    for (int r = 0; r < 4; r++) {
                        int row = rowb + am * 16 + r;
                        float v = acc[am][an][r] + bv[an];
                        float w = xch[sl * 8192 + pbase + an * 256 + r * 64];
                        float ang = (float)row * invf[an];
                        float rev = ang * 0.15915494309f;
                        rev -= floorf(rev);
                        float arad = rev * 6.28318530718f;
                        float sn = __sinf(arad), cs = __cosf(arad);
                        float o = ((wn & 1) == 0) ? (v * cs - w * sn) : (v * cs + w * sn);
                        C[(size_t)row * EDIM + col] = f2bf(o * psc);
                    }
                }
            }
        }
    }
}

// ---------------- bf16 GEMM: C = A * B^T + bias (m97 structure) ----------------
// Used for the output projection (KSPLIT=2, 512 blocks = 2/CU) and the
// no-split fallback.
template <typename OUTT, int KSPLIT>
__global__ __launch_bounds__(256) void gemm_bt(
    const ushort* __restrict__ A,
    const ushort* __restrict__ B0, const ushort* __restrict__ B1, const ushort* __restrict__ B2,
    const float* __restrict__ s0, const float* __restrict__ s1, const float* __restrict__ s2,
    OUTT* __restrict__ C0, OUTT* __restrict__ C1, OUTT* __restrict__ C2,
    int nbpm)
{
    __shared__ __align__(16) ushort smem[2 * 128 * 32];
    ushort* a_s = smem;
    ushort* b_s = smem + 128 * 32;

    const int tid = threadIdx.x;
    const int wave = tid >> 6, lane = tid & 63;
    const int l15 = lane & 15, quad = lane >> 4;
    const int wm = wave & 1, wn = wave >> 1;
    const int bm = blockIdx.x * 128;
    const int which = blockIdx.y / nbpm;
    const int n0 = (blockIdx.y % nbpm) * 128;

    const ushort* B;
    const float*  bia;
    OUTT*         C;
    const ushort* Abase;
    if constexpr (KSPLIT == 2) {
        B = B0; bia = s0; C = C0;
        Abase = A + which * (EDIM / 2);
    } else {
        B   = (which == 0) ? B0 : (which == 1) ? B1 : B2;
        bia = (which == 0) ? s0 : (which == 1) ? s1 : s2;
        C   = (which == 0) ? C0 : (which == 1) ? C1 : C2;
        Abase = A;
    }
    const ushort* Bbase = (KSPLIT == 2) ? B + which * (EDIM / 2) : B;

    floatx4 acc[4][4];
#pragma unroll
    for (int i = 0; i < 4; i++)
#pragma unroll
        for (int j = 0; j < 4; j++) acc[i][j] = (floatx4)0.0f;

    const int t1 = tid + 256;
    const int row0 = tid >> 2, kc0 = (tid & 3) * 8;
    const int row1 = t1 >> 2,  kc1 = (t1 & 3) * 8;

    for (int k0 = 0; k0 < EDIM / KSPLIT; k0 += 32) {
        __syncthreads();
        gload_lds16(Abase + (size_t)(bm + row0) * EDIM + k0 + kc0, a_s + tid * 8);
        gload_lds16(Abase + (size_t)(bm + row1) * EDIM + k0 + kc1, a_s + t1 * 8);
        gload_lds16(Bbase + (size_t)(n0 + row0) * EDIM + k0 + kc0, b_s + tid * 8);
        gload_lds16(Bbase + (size_t)(n0 + row1) * EDIM + k0 + kc1, b_s + t1 * 8);
        __syncthreads();

        short8 af[4], bf[4];
#pragma unroll
        for (int mt = 0; mt < 4; mt++)
            af[mt] = *(const short8*)(a_s + (wm * 64 + mt * 16 + l15) * 32 + quad * 8);
#pragma unroll
        for (int nt = 0; nt < 4; nt++)
            bf[nt] = *(const short8*)(b_s + (wn * 64 + nt * 16 + l15) * 32 + quad * 8);
#pragma unroll
        for (int mt = 0; mt < 4; mt++)
#pragma unroll
            for (int nt = 0; nt < 4; nt++)
                acc[mt][nt] = __builtin_amdgcn_mfma_f32_16x16x32_bf16(af[mt], bf[nt], acc[mt][nt], 0, 0, 0);
    }

    if constexpr (KSPLIT == 2) {
#pragma unroll
        for (int nt = 0; nt < 4; nt++) {
            int col = n0 + wn * 64 + nt * 16 + l15;
            float bv = (which == 0) ? bia[col] : 0.0f;
#pragma unroll
            for (int mt = 0; mt < 4; mt++) {
#pragma unroll
                for (int r = 0; r < 4; r++) {
                    int row = bm + wm * 64 + mt * 16 + quad * 4 + r;
                    atomicAdd(&((float*)C)[(size_t)row * EDIM + col], acc[mt][nt][r] + bv);
                }
            }
        }
    } else {
#pragma unroll
        for (int nt = 0; nt < 4; nt++) {
            int col = n0 + wn * 64 + nt * 16 + l15;
            float bv = bia[col];
#pragma unroll
            for (int mt = 0; mt < 4; mt++) {
#pragma unroll
                for (int r = 0; r < 4; r++) {
                    int row = bm + wm * 64 + mt * 16 + quad * 4 + r;
                    float v = acc[mt][nt][r] + bv;
                    if constexpr (sizeof(OUTT) == 2)
                        ((ushort*)C)[(size_t)row * EDIM + col] = f2bf(v);
                    else
                        ((float*)C)[(size_t)row * EDIM + col] = v;
                }
            }
        }
    }
}

// ---------------- flash attention: S^T trick + fixed-max softmax ----------------
// s_setprio around MFMA clusters (T5). nsplit=2: grid 1024 = 4 blocks/CU
// (LDS exactly 40960 B — do not add any __shared__ bytes; +512 B drops to
// 3 blocks/CU and ~3x the runtime, R7). Direct uint4 global->LDS staging
// (R10 lesson: reg-held prefetch across barriers spills to scratch).
#define MFIX2 17.31234049f   // 12 * log2(e)
__global__ __launch_bounds__(256, 4) void attn_kernel(
    const ushort* __restrict__ Q, const ushort* __restrict__ K,
    const ushort* __restrict__ Vtg,
    ushort* __restrict__ Opart, float* __restrict__ Lsum,
    ushort* __restrict__ Ab, int nsplit)
{
    __shared__ __align__(16) ushort Ks[64 * 128];
    __shared__ __align__(16) ushort Vt[128 * 64];
    __shared__ __align__(16) ushort Ps[64 * 64];

    const int bid = blockIdx.x;
    const int head = bid & 15, qt = (bid >> 4) & 31, half = bid >> 9;
    const int tid = threadIdx.x, wave = tid >> 6, lane = tid & 63;
    const int l15 = lane & 15, quad = lane >> 4;
    const int l7 = l15 & 7;
    const int kstart = half * (SDIM / nsplit);
    const int ntile = (SDIM / nsplit) / 64;

    short8 qf[4];
    {
        int s = qt * 64 + wave * 16 + l15;
        const ushort* qp = Q + (size_t)s * EDIM + head * DHEAD;
#pragma unroll
        for (int kc = 0; kc < 4; kc++) qf[kc] = *(const short8*)(qp + kc * 32 + quad * 8);
    }

    floatx4 o[8];
#pragma unroll
    for (int i = 0; i < 8; i++) o[i] = (floatx4)0.0f;
    float lsum = 0.0f;

    const int krow = tid >> 4, kc8 = tid & 15;
    const int vd = tid >> 3, vc8 = tid & 7;
    const int prow = wave * 16 + l15;

    for (int kv = 0; kv < ntile; kv++) {
        const int k0 = kstart + kv * 64;
        __syncthreads();
#pragma unroll
        for (int i = 0; i < 4; i++) {
            int row = krow + i * 16;
            uint4 v = *(const uint4*)(K + (size_t)(k0 + row) * EDIM + head * DHEAD + kc8 * 8);
            *(uint4*)(Ks + row * 128 + ((kc8 ^ (row & 7)) << 3)) = v;
        }
#pragma unroll
        for (int i = 0; i < 4; i++) {
            int d = vd + i * 32;
            uint4 v = *(const uint4*)(Vtg + (size_t)head * SDIM * DHEAD + (size_t)d * SDIM + k0 + vc8 * 8);
            *(uint4*)(Vt + d * 64 + ((vc8 ^ (d & 7)) << 3)) = v;
        }
        __syncthreads();

#pragma unroll
        for (int nt = 0; nt < 4; nt++) {
            floatx4 st = (floatx4)0.0f;
            __builtin_amdgcn_s_setprio(1);
#pragma unroll
            for (int kc = 0; kc < 4; kc++) {
                short8 kfr = *(const short8*)(Ks + (nt * 16 + l15) * 128 + (((kc * 4 + quad) ^ l7) << 3));
                st = __builtin_amdgcn_mfma_f32_16x16x32_bf16(kfr, qf[kc], st, 0, 0, 0);
            }
            __builtin_amdgcn_s_setprio(0);
            ushort4 pk;
            float p0 = __builtin_amdgcn_exp2f(st[0] - MFIX2);
            float p1 = __builtin_amdgcn_exp2f(st[1] - MFIX2);
            float p2 = __builtin_amdgcn_exp2f(st[2] - MFIX2);
            float p3 = __builtin_amdgcn_exp2f(st[3] - MFIX2);
            lsum += (p0 + p1) + (p2 + p3);
            pk.x = f2bf(p0); pk.y = f2bf(p1); pk.z = f2bf(p2); pk.w = f2bf(p3);
            int c2 = (nt * 2 + (quad >> 1)) ^ l7;
            *(ushort4*)(Ps + prow * 64 + (c2 << 3) + ((quad & 1) << 2)) = pk;
        }

        __builtin_amdgcn_s_setprio(1);
#pragma unroll
        for (int kc2 = 0; kc2 < 2; kc2++) {
            short8 af = *(const short8*)(Ps + prow * 64 + (((kc2 * 4 + quad) ^ l7) << 3));
#pragma unroll
            for (int nt2 = 0; nt2 < 8; nt2++) {
                short8 bfr = *(const short8*)(Vt + (nt2 * 16 + l15) * 64 + (((kc2 * 4 + quad) ^ l7) << 3));
                o[nt2] = __builtin_amdgcn_mfma_f32_16x16x32_bf16(af, bfr, o[nt2], 0, 0, 0);
            }
        }
        __builtin_amdgcn_s_setprio(0);
    }

    lsum += __shfl_xor(lsum, 16);
    lsum += __shfl_xor(lsum, 32);

    if (nsplit == 1) {
        float invl[4];
#pragma unroll
        for (int r = 0; r < 4; r++) invl[r] = 1.0f / __shfl(lsum, quad * 4 + r, 16);
#pragma unroll
        for (int nt2 = 0; nt2 < 8; nt2++) {
#pragma unroll
            for (int r = 0; r < 4; r++) {
                int s = qt * 64 + wave * 16 + quad * 4 + r;
                int d = nt2 * 16 + l15;
                Ab[(size_t)head * SDIM * DHEAD + (size_t)s * DHEAD + d] = f2bf(o[nt2][r] * invl[r]);
            }
        }
    } else {
        size_t pb = ((size_t)half * NHEAD + head) * SDIM * DHEAD;
#pragma unroll
        for (int nt2 = 0; nt2 < 8; nt2++) {
#pragma unroll
            for (int r = 0; r < 4; r++) {
                int s = qt * 64 + wave * 16 + quad * 4 + r;
                int d = nt2 * 16 + l15;
                Opart[pb + (size_t)s * DHEAD + d] = f2bf(o[nt2][r]);
            }
        }
        if (lane < 16)
            Lsum[((size_t)half * NHEAD + head) * SDIM + qt * 64 + wave * 16 + lane] = lsum;
    }
}

// ---------------- merge two KV-split partials (shared fixed max) ----------------
// (out-zeroing moved to QKV filler blocks in R12)
__global__ void merge_kernel(const ushort* __restrict__ Opart,
                             const float* __restrict__ Lsum,
                             ushort* __restrict__ Ab)
{
    const int HS = NHEAD * SDIM;
    int t = blockIdx.x * blockDim.x + threadIdx.x;
    int row = t >> 4, c8 = (t & 15) * 8;
    float inv = 1.0f / (Lsum[row] + Lsum[HS + row]);
    float acc[8] = {0, 0, 0, 0, 0, 0, 0, 0};
#pragma unroll
    for (int p = 0; p < 2; p++) {
        union { uint4 v; ushort u[8]; } a;
        a.v = *(const uint4*)(Opart + (size_t)p * HS * DHEAD + (size_t)row * DHEAD + c8);
#pragma unroll
        for (int j = 0; j < 8; j++) acc[j] += bf2f(a.u[j]);
    }
    union { uint4 v; ushort u[8]; } ro;
#pragma unroll
    for (int j = 0; j < 8; j++) ro.u[j] = f2bf(acc[j] * inv);
    *(uint4*)(Ab + (size_t)row * DHEAD + c8) = ro.v;
}

extern "C" void kernel_launch(void* const* d_in, const int* in_sizes, int n_in,
                              void* d_out, int out_size, void* d_ws, size_t ws_size,
                              hipStream_t stream) {
    (void)in_sizes; (void)n_in; (void)out_size;
    const float* x  = (const float*)d_in[0];
    const float* Wq = (const float*)d_in[1];
    const float* bq = (const float*)d_in[2];
    const float* Wk = (const float*)d_in[3];
    const float* bk = (const float*)d_in[4];
    const float* Wv = (const float*)d_in[5];
    const float* bv = (const float*)d_in[6];
    const float* Wo = (const float*)d_in[7];
    const float* bo = (const float*)d_in[8];
    float* out = (float*)d_out;

    char* ws = (char*)d_ws;
    const size_t SEG = (size_t)EDIM * EDIM * 2;  // 8 MB per bf16 matrix
    ushort* xb  = (ushort*)(ws + 0 * SEG);
    ushort* Wqb = (ushort*)(ws + 1 * SEG);
    ushort* Wkb = (ushort*)(ws + 2 * SEG);
    ushort* Wvb = (ushort*)(ws + 3 * SEG);
    ushort* Wob = (ushort*)(ws + 4 * SEG);
    ushort* Qb  = (ushort*)(ws + 5 * SEG);
    ushort* Kb  = (ushort*)(ws + 6 * SEG);
    ushort* Vtg = (ushort*)(ws + 7 * SEG);   // V pre-transposed [h][d][s]
    ushort* Ab  = (ushort*)(ws + 8 * SEG);
    ushort* Op  = (ushort*)(ws + 0 * SEG);   // attn partials reuse SEG0-1 (2 x 8MB)
    float*  Ls  = (float*)(ws + 11 * SEG);   // 2 x 32768 x 4B = 256KB

    const int split = (ws_size >= ((size_t)89 << 20)) ? 1 : 0;

    // x, Wq, Wk, Wv converted up front; Wo + out-zero inside the QKV launch
    convert4_kernel<<<dim3(512, 4), 256, 0, stream>>>(
        x, Wq, Wk, Wv, xb, Wqb, Wkb, Wvb);

    // fused QKV projection (192 GEMM blocks) + Wo convert + out zero (64 fillers)
    gemm256_qkv<<<dim3(8, 32), 512, 0, stream>>>(
        xb, Wqb, Wkb, Wvb, bq, bk, bv, Qb, Kb, Vtg, Wo, Wob, out);

    if (split) {
        // 2-way KV-split attention: 1024 blocks = exactly 4/CU resident
        attn_kernel<<<1024, 256, 0, stream>>>(Qb, Kb, Vtg, Op, Ls, Ab, 2);
        merge_kernel<<<2048, 256, 0, stream>>>(Op, Ls, Ab);
        // out-projection: m97 128^2 K-split-2 (512 blocks = 2/CU),
        // atomicAdd into the out buffer zeroed by the QKV fillers
        gemm_bt<float, 2><<<dim3(16, 32), 256, 0, stream>>>(
            Ab, Wob, Wob, Wob, bo, bo, bo, out, out, out, 16);
    } else {
        attn_kernel<<<512, 256, 0, stream>>>(Qb, Kb, Vtg, Op, Ls, Ab, 1);
        gemm_bt<float, 1><<<dim3(16, 16), 256, 0, stream>>>(
            Ab, Wob, Wob, Wob, bo, bo, bo, out, out, out, 16);
    }
}